// Round 1
// baseline (547.355 us; speedup 1.0000x reference)
//
#include <hip/hip_runtime.h>

typedef unsigned short u16;
typedef __bf16 bf16x8 __attribute__((ext_vector_type(8)));
typedef float f32x4 __attribute__((ext_vector_type(4)));
typedef unsigned short u16x4 __attribute__((ext_vector_type(4)));

// fp32 -> bf16 round-to-nearest-even (bit twiddle; no NaNs in this problem)
__device__ __forceinline__ u16 f2bf(float f) {
  unsigned int u = __builtin_bit_cast(unsigned int, f);
  u += 0x7FFFu + ((u >> 16) & 1u);
  return (u16)(u >> 16);
}

// sign(f) as bf16 bits: +1 -> 0x3F80, -1 -> 0xBF80, 0 -> 0
__device__ __forceinline__ u16 signbf(float f) {
  return f > 0.f ? (u16)0x3F80u : (f < 0.f ? (u16)0xBF80u : (u16)0u);
}

// async global->LDS, 16B per lane; LDS dest = wave-uniform base + lane*16
__device__ __forceinline__ void lds_load16(const void* g, void* l) {
  __builtin_amdgcn_global_load_lds(
      (const __attribute__((address_space(1))) unsigned int*)g,
      (__attribute__((address_space(3))) unsigned int*)l, 16, 0, 0);
}

// ---------------- convert x (fp32 [M][K]) -> xb (bf16 [M][K]) ----------------
__global__ void cvt_x(const float* __restrict__ x, u16* __restrict__ xb, long long nv) {
  long long stride = (long long)gridDim.x * blockDim.x;
  for (long long i = (long long)blockIdx.x * blockDim.x + threadIdx.x; i < nv; i += stride) {
    float4 v = reinterpret_cast<const float4*>(x)[i];
    u16x4 o = { f2bf(v.x), f2bf(v.y), f2bf(v.z), f2bf(v.w) };
    reinterpret_cast<u16x4*>(xb)[i] = o;
  }
}

// -------- convert+transpose W (fp32 [K][N]) -> wt (sign-bf16 [N][K]) --------
__global__ void cvt_w(const float* __restrict__ W, u16* __restrict__ wt, int K, int N) {
  __shared__ u16 t[32][34];  // +2 u16 pad: read banks fully spread (stride 17 banks)
  int n0 = blockIdx.x * 32, k0 = blockIdx.y * 32;
  int tx = threadIdx.x, ty = threadIdx.y;  // block (32, 8)
#pragma unroll
  for (int r = 0; r < 4; ++r) {
    int k = ty + r * 8;
    t[k][tx] = signbf(W[(long long)(k0 + k) * N + n0 + tx]);
  }
  __syncthreads();
#pragma unroll
  for (int r = 0; r < 4; ++r) {
    int n = ty + r * 8;
    wt[(long long)(n0 + n) * K + k0 + tx] = t[tx][n];
  }
}

// ---------------- bf16 MFMA GEMM: y[M][N] = xb[M][K] * wt[N][K]^T ----------------
// m97 structure: 128x128 tile, BK=64, 4 waves (2x2), 4x4 frags of 16x16x32, 2-barrier loop.
// XPRE=1: A staged via global_load_lds from pre-converted xb.
// XPRE=0: A loaded fp32 from x, converted in-register, ds_written (ws too small for xb).
template <int XPRE>
__global__ __launch_bounds__(256) void gemm_sign(
    const float* __restrict__ xf, const u16* __restrict__ xb,
    const u16* __restrict__ wt, float* __restrict__ y, int M, int N, int K) {
  __shared__ u16 As[128 * 64];
  __shared__ u16 Bs[128 * 64];

  const int tid = threadIdx.x;
  const int lane = tid & 63;
  const int w = tid >> 6;

  const int nbx = N >> 7;
  const int bx = blockIdx.x % nbx;
  const int by = blockIdx.x / nbx;
  const long long bm0 = (long long)by << 7;
  const long long bn0 = (long long)bx << 7;

  const int wm = (w >> 1) << 6;  // wave row origin in tile
  const int wn = (w & 1) << 6;   // wave col origin in tile
  const int lr = lane & 15;
  const int lg = lane >> 4;

  f32x4 acc[4][4];
#pragma unroll
  for (int i = 0; i < 4; ++i)
#pragma unroll
    for (int j = 0; j < 4; ++j)
      acc[i][j] = f32x4{0.f, 0.f, 0.f, 0.f};

  // global_load_lds staging geometry: per wave 4 calls cover a 32-row band (8 rows/call)
  const int srow = w * 32 + (lane >> 3);
  const int scol = (lane & 7) * 8;
  const u16* aglb = XPRE ? (xb + (bm0 + srow) * K + scol) : nullptr;
  const u16* bglb = wt + (bn0 + srow) * K + scol;
  u16* AsW = &As[(w * 32) * 64];
  u16* BsW = &Bs[(w * 32) * 64];

  // reg-staging geometry (XPRE==0): 8 iters x (16 rows x 64 cols), float4 per thread
  const int xrow = tid >> 4;
  const int xcol = (tid & 15) * 4;
  const float* xglb = XPRE ? nullptr : (xf + (bm0 + xrow) * K + xcol);

  const int nkt = K >> 6;
  for (int kt = 0; kt < nkt; ++kt) {
    if (kt) __syncthreads();  // prev compute done before overwrite
    const int kofs = kt * 64;
    if (XPRE) {
#pragma unroll
      for (int it = 0; it < 4; ++it)
        lds_load16(aglb + (long long)it * 8 * K + kofs, AsW + it * 8 * 64);
    } else {
#pragma unroll
      for (int i = 0; i < 8; ++i) {
        float4 v = *reinterpret_cast<const float4*>(xglb + (long long)i * 16 * K + kofs);
        u16x4 o = { f2bf(v.x), f2bf(v.y), f2bf(v.z), f2bf(v.w) };
        *reinterpret_cast<u16x4*>(&As[(xrow + i * 16) * 64 + xcol]) = o;
      }
    }
#pragma unroll
    for (int it = 0; it < 4; ++it)
      lds_load16(bglb + (long long)it * 8 * K + kofs, BsW + it * 8 * 64);

    __syncthreads();  // compiler drains vmcnt+lgkmcnt before s_barrier

    const u16* Ab = &As[(wm + lr) * 64 + lg * 8];
    const u16* Bb = &Bs[(wn + lr) * 64 + lg * 8];
#pragma unroll
    for (int ks = 0; ks < 2; ++ks) {
      bf16x8 a[4], b[4];
#pragma unroll
      for (int mi = 0; mi < 4; ++mi)
        a[mi] = *reinterpret_cast<const bf16x8*>(Ab + mi * 16 * 64 + ks * 32);
#pragma unroll
      for (int ni = 0; ni < 4; ++ni)
        b[ni] = *reinterpret_cast<const bf16x8*>(Bb + ni * 16 * 64 + ks * 32);
#pragma unroll
      for (int mi = 0; mi < 4; ++mi)
#pragma unroll
        for (int ni = 0; ni < 4; ++ni)
          acc[mi][ni] = __builtin_amdgcn_mfma_f32_16x16x32_bf16(a[mi], b[ni], acc[mi][ni], 0, 0, 0);
    }
  }

  // C/D layout (verified m89/m91): col = lane&15, row = (lane>>4)*4 + reg
  float* yb = y + (bm0 + wm + lg * 4) * N + bn0 + wn + lr;
#pragma unroll
  for (int mi = 0; mi < 4; ++mi)
#pragma unroll
    for (int r = 0; r < 4; ++r)
#pragma unroll
      for (int ni = 0; ni < 4; ++ni)
        yb[(long long)(mi * 16 + r) * N + ni * 16] = acc[mi][ni][r];
}

// ---------------- emergency fallback (no usable scratch): naive fp32 ----------------
__global__ void naive_gemm(const float* __restrict__ x, const float* __restrict__ W,
                           float* __restrict__ y, int M, int N, int K) {
  long long i = (long long)blockIdx.x * blockDim.x + threadIdx.x;
  if (i >= (long long)M * N) return;
  int m = (int)(i / N), n = (int)(i % N);
  const float* xr = x + (long long)m * K;
  float acc = 0.f;
  for (int k = 0; k < K; ++k) {
    float wv = W[(long long)k * N + n];
    acc += (wv > 0.f ? xr[k] : (wv < 0.f ? -xr[k] : 0.f));
  }
  y[i] = acc;
}

extern "C" void kernel_launch(void* const* d_in, const int* in_sizes, int n_in,
                              void* d_out, int out_size, void* d_ws, size_t ws_size,
                              hipStream_t stream) {
  const float* x = (const float*)d_in[0];
  const float* W = (const float*)d_in[1];
  float* y = (float*)d_out;
  const int K = 4096, N = 4096;
  const int M = in_sizes[0] / K;  // 8192

  const size_t xb_bytes = (size_t)M * K * sizeof(u16);  // 64 MB
  const size_t wt_bytes = (size_t)K * N * sizeof(u16);  // 32 MB

  if (ws_size < wt_bytes) {
    long long tot = (long long)M * N;
    int blocks = (int)((tot + 255) / 256);
    naive_gemm<<<blocks, 256, 0, stream>>>(x, W, y, M, N, K);
    return;
  }

  const bool xpre = ws_size >= xb_bytes + wt_bytes;
  u16* xb = nullptr;
  u16* wt;
  if (xpre) { xb = (u16*)d_ws; wt = xb + (size_t)M * K; }
  else      { wt = (u16*)d_ws; }

  dim3 wgrid(N / 32, K / 32), wblk(32, 8);
  cvt_w<<<wgrid, wblk, 0, stream>>>(W, wt, K, N);
  if (xpre)
    cvt_x<<<2048, 256, 0, stream>>>(x, xb, (long long)M * K / 4);

  dim3 ggrid((M / 128) * (N / 128)), gblk(256);
  if (xpre) gemm_sign<1><<<ggrid, gblk, 0, stream>>>(x, xb, wt, y, M, N, K);
  else      gemm_sign<0><<<ggrid, gblk, 0, stream>>>(x, xb, wt, y, M, N, K);
}

// Round 3
// 502.777 us; speedup vs baseline: 1.0887x; 1.0887x over previous
//
#include <hip/hip_runtime.h>

typedef unsigned short u16;
typedef __bf16 bf16x8 __attribute__((ext_vector_type(8)));
typedef float f32x4 __attribute__((ext_vector_type(4)));
typedef unsigned short u16x4 __attribute__((ext_vector_type(4)));

// fp32 -> bf16 round-to-nearest-even (bit twiddle; no NaNs in this problem)
__device__ __forceinline__ u16 f2bf(float f) {
  unsigned int u = __builtin_bit_cast(unsigned int, f);
  u += 0x7FFFu + ((u >> 16) & 1u);
  return (u16)(u >> 16);
}

// sign(f) as bf16 bits: +1 -> 0x3F80, -1 -> 0xBF80, 0 -> 0
__device__ __forceinline__ u16 signbf(float f) {
  return f > 0.f ? (u16)0x3F80u : (f < 0.f ? (u16)0xBF80u : (u16)0u);
}

// async global->LDS, 16B/lane; LDS dest = wave-uniform base + lane*16
__device__ __forceinline__ void lds_load16(const void* g, void* l) {
  __builtin_amdgcn_global_load_lds(
      (const __attribute__((address_space(1))) unsigned int*)g,
      (__attribute__((address_space(3))) unsigned int*)l, 16, 0, 0);
}

// ---------------- convert x (fp32 [M][K]) -> xb (bf16 [M][K]) ----------------
__global__ void cvt_x(const float* __restrict__ x, u16* __restrict__ xb, long long nv) {
  long long stride = (long long)gridDim.x * blockDim.x;
  for (long long i = (long long)blockIdx.x * blockDim.x + threadIdx.x; i < nv; i += stride) {
    float4 v = reinterpret_cast<const float4*>(x)[i];
    u16x4 o = { f2bf(v.x), f2bf(v.y), f2bf(v.z), f2bf(v.w) };
    reinterpret_cast<u16x4*>(xb)[i] = o;
  }
}

// -------- convert+transpose W (fp32 [K][N]) -> wt (sign-bf16 [N][K]) --------
__global__ void cvt_w(const float* __restrict__ W, u16* __restrict__ wt, int K, int N) {
  __shared__ u16 t[32][34];
  int n0 = blockIdx.x * 32, k0 = blockIdx.y * 32;
  int tx = threadIdx.x, ty = threadIdx.y;  // block (32, 8)
#pragma unroll
  for (int r = 0; r < 4; ++r) {
    int k = ty + r * 8;
    t[k][tx] = signbf(W[(long long)(k0 + k) * N + n0 + tx]);
  }
  __syncthreads();
#pragma unroll
  for (int r = 0; r < 4; ++r) {
    int n = ty + r * 8;
    wt[(long long)(n0 + n) * K + k0 + tx] = t[tx][n];
  }
}

// ---------------- 256x256 8-phase counted-vmcnt GEMM ----------------
// y[M][N] = xb[M][K] * wt[N][K]^T.  8 waves (2M x 4N), BK=64, 128 KiB LDS.
// LDS map (u16 idx): A(buf,ks) = buf*16384 + ks*8192, [256 rows][32], 64B rows.
//                    B(buf,ks) = 32768 + same.
// Swizzle: 16B chunk g stored at g ^ ((row>>1)&3); gload_lds keeps LDS linear,
// the SOURCE address is pre-swizzled per-lane: chunk = (l&3)^((l>>3)&3).
// Half-tile stream per tile t: {A_ks0, B_ks0, A_ks1, B_ks1}; 1 half issued per
// phase at distance 6; vmcnt(4) once per K-tile (vmcnt(0) at t==nkt-2 tail).
__global__ __launch_bounds__(512, 2) void gemm8p(
    const u16* __restrict__ xb, const u16* __restrict__ wt,
    float* __restrict__ y, int M, int N, int K) {
  extern __shared__ u16 lds[];  // 131072 B

  const int tid = threadIdx.x;
  const int lane = tid & 63;
  const int w = tid >> 6;

  // bijective XCD swizzle (nwg % 8 == 0)
  const int nbx = N >> 8;
  int wg = blockIdx.x;
  const int nwg = gridDim.x;
  if ((nwg & 7) == 0) wg = (wg & 7) * (nwg >> 3) + (wg >> 3);
  const int by = wg / nbx, bx = wg % nbx;
  const long long bm0 = (long long)by << 8;
  const long long bn0 = (long long)bx << 8;

  const int lr = lane & 15, lg = lane >> 4;
  const int wm0 = (w >> 2) * 128;  // wave M origin (local)
  const int wn0 = (w & 3) * 64;    // wave N origin (local)

  // swizzled ds_read offsets (u16): row*32 + (chunk^((row>>1)&3))*8
  const int rswz = (lr >> 1) & 3;
  const int aoff = (wm0 + lr) * 32 + ((lg ^ rswz) << 3);
  const int boff = (wn0 + lr) * 32 + ((lg ^ rswz) << 3);

  // staging geometry: per call, wave covers 16 rows x 64B; 2 calls per half
  const int schunk = (lane & 3) ^ ((lane >> 3) & 3);  // pre-swizzled source chunk
  const int srow = lane >> 2;                         // 0..15
  const u16* asrc = xb + (bm0 + w * 32 + srow) * (long long)K + schunk * 8;
  const u16* bsrc = wt + (bn0 + w * 32 + srow) * (long long)K + schunk * 8;
  u16* aldsw = lds + w * 1024;           // + buf*16384 + ks*8192 + it*512
  u16* bldsw = lds + 32768 + w * 1024;

  f32x4 acc[8][4];
#pragma unroll
  for (int i = 0; i < 8; ++i)
#pragma unroll
    for (int j = 0; j < 4; ++j)
      acc[i][j] = f32x4{0.f, 0.f, 0.f, 0.f};

  const int nkt = K >> 6;

  auto stageA = [&](int t, int ks) {
    const u16* s = asrc + t * 64 + ks * 32;
    u16* d = aldsw + (t & 1) * 16384 + ks * 8192;
#pragma unroll
    for (int it = 0; it < 2; ++it)
      lds_load16(s + (long long)it * 16 * K, d + it * 512);
  };
  auto stageB = [&](int t, int ks) {
    const u16* s = bsrc + t * 64 + ks * 32;
    u16* d = bldsw + (t & 1) * 16384 + ks * 8192;
#pragma unroll
    for (int it = 0; it < 2; ++it)
      lds_load16(s + (long long)it * 16 * K, d + it * 512);
  };

  // prologue: issue halves h0..h5 (tile0 complete + tile1 ks0), wait tile0
  stageA(0, 0); stageB(0, 0); stageA(0, 1); stageB(0, 1);
  stageA(1, 0); stageB(1, 0);
  asm volatile("s_waitcnt vmcnt(4)" ::: "memory");
  __builtin_amdgcn_s_barrier();

  bf16x8 a[8];

  // one phase: optional A-frag reload, 2 B-frag reads, 1 half-tile stage issue,
  // barrier, 16 MFMA under setprio(1).  qks/qnp are compile-time literals.
#define PHASE(qks, qnp, RDA, STAGE_STMT)                                        \
  {                                                                             \
    const int lbase = (t & 1) * 16384 + (qks)*8192;                             \
    if (RDA) {                                                                  \
      _Pragma("unroll") for (int mf = 0; mf < 8; ++mf)                          \
          a[mf] = *(const bf16x8*)&lds[lbase + aoff + mf * 512];                \
    }                                                                           \
    bf16x8 b0 = *(const bf16x8*)&lds[32768 + lbase + boff + ((qnp)*2) * 512];   \
    bf16x8 b1 = *(const bf16x8*)&lds[32768 + lbase + boff + ((qnp)*2 + 1) * 512]; \
    STAGE_STMT;                                                                 \
    __builtin_amdgcn_s_barrier();                                               \
    __builtin_amdgcn_s_setprio(1);                                              \
    _Pragma("unroll") for (int mf = 0; mf < 8; ++mf) {                          \
      acc[mf][(qnp)*2] = __builtin_amdgcn_mfma_f32_16x16x32_bf16(               \
          a[mf], b0, acc[mf][(qnp)*2], 0, 0, 0);                                \
      acc[mf][(qnp)*2 + 1] = __builtin_amdgcn_mfma_f32_16x16x32_bf16(           \
          a[mf], b1, acc[mf][(qnp)*2 + 1], 0, 0, 0);                            \
    }                                                                           \
    __builtin_amdgcn_s_setprio(0);                                              \
  }

  for (int t = 0; t < nkt; ++t) {
    // q0: ks=0, nf{0,1}; issue tile t+1 A_ks1
    PHASE(0, 0, true,  { if (t + 1 < nkt) stageA(t + 1, 1); })
    __builtin_amdgcn_s_barrier();
    // q1: ks=0, nf{2,3}; issue tile t+1 B_ks1
    PHASE(0, 1, false, { if (t + 1 < nkt) stageB(t + 1, 1); })
    __builtin_amdgcn_s_barrier();
    // q2: ks=1, nf{0,1}; issue tile t+2 A_ks0
    PHASE(1, 0, true,  { if (t + 2 < nkt) stageA(t + 2, 0); })
    __builtin_amdgcn_s_barrier();
    // q3: ks=1, nf{2,3}; issue tile t+2 B_ks0; group-end counted wait
    PHASE(1, 1, false, { if (t + 2 < nkt) stageB(t + 2, 0); })
    if (t == nkt - 2)     asm volatile("s_waitcnt vmcnt(0)" ::: "memory");
    else if (t < nkt - 2) asm volatile("s_waitcnt vmcnt(4)" ::: "memory");
    __builtin_amdgcn_s_barrier();
  }
#undef PHASE

  // C/D layout (verified r1): col = lane&15, row = (lane>>4)*4 + reg
  float* yb = y + (bm0 + wm0 + lg * 4) * N + bn0 + wn0 + lr;
#pragma unroll
  for (int mf = 0; mf < 8; ++mf)
#pragma unroll
    for (int r = 0; r < 4; ++r)
#pragma unroll
      for (int nf = 0; nf < 4; ++nf)
        yb[(long long)(mf * 16 + r) * N + nf * 16] = acc[mf][nf][r];
}

// ---------------- emergency fallback: naive fp32 ----------------
__global__ void naive_gemm(const float* __restrict__ x, const float* __restrict__ W,
                           float* __restrict__ y, int M, int N, int K) {
  long long i = (long long)blockIdx.x * blockDim.x + threadIdx.x;
  if (i >= (long long)M * N) return;
  int m = (int)(i / N), n = (int)(i % N);
  const float* xr = x + (long long)m * K;
  float acc = 0.f;
  for (int k = 0; k < K; ++k) {
    float wv = W[(long long)k * N + n];
    acc += (wv > 0.f ? xr[k] : (wv < 0.f ? -xr[k] : 0.f));
  }
  y[i] = acc;
}

extern "C" void kernel_launch(void* const* d_in, const int* in_sizes, int n_in,
                              void* d_out, int out_size, void* d_ws, size_t ws_size,
                              hipStream_t stream) {
  const float* x = (const float*)d_in[0];
  const float* W = (const float*)d_in[1];
  float* y = (float*)d_out;
  const int K = 4096, N = 4096;
  const int M = in_sizes[0] / K;  // 8192

  const size_t xb_bytes = (size_t)M * K * sizeof(u16);  // 64 MB
  const size_t wt_bytes = (size_t)K * N * sizeof(u16);  // 32 MB

  if (ws_size < xb_bytes + wt_bytes || (M & 255) || (N & 255) || (K & 127)) {
    long long tot = (long long)M * N;
    naive_gemm<<<(int)((tot + 255) / 256), 256, 0, stream>>>(x, W, y, M, N, K);
    return;
  }

  u16* xb = (u16*)d_ws;
  u16* wt = xb + (size_t)M * K;

  dim3 wgrid(N / 32, K / 32), wblk(32, 8);
  cvt_w<<<wgrid, wblk, 0, stream>>>(W, wt, K, N);
  cvt_x<<<4096, 256, 0, stream>>>(x, xb, (long long)M * K / 4);

  hipFuncSetAttribute(reinterpret_cast<const void*>(gemm8p),
                      hipFuncAttributeMaxDynamicSharedMemorySize, 131072);
  dim3 ggrid((M / 256) * (N / 256));
  gemm8p<<<ggrid, dim3(512), 131072, stream>>>(xb, wt, y, M, N, K);
}